// Round 2
// baseline (6097.428 us; speedup 1.0000x reference)
//
#include <hip/hip_runtime.h>
#include <cstdint>
#include <cstddef>

#define B_Q   1024
#define N_K   131072
#define DIM   256
#define TOPK  32
#define EPSN  1e-12f

// main kernel config
#define NRANGES 16              // key ranges (blocks in x)
#define QGROUPS 16              // query groups (blocks in y)
#define QT      64              // queries per block
#define WQ      8               // queries per wave
#define NT      1024            // keys per tile
#define NTILES  8               // (N_K/NRANGES)/NT
#define CAP     160             // candidate list capacity per (q, range)
#define FLUSH_AT 96             // flush when cnt exceeds this
// bound proof: at each j-check cnt<=FLUSH_AT (else flushed to 32); one j adds
// <=64 appends per query => cnt <= 96+64 = 160 = CAP. never overflows.

typedef unsigned long long u64;
typedef unsigned int u32;

// ---------------- K1: qn = normalize(query @ W^T + b), row-major [B_Q][DIM] --
__global__ __launch_bounds__(256) void qn_kernel(
    const float* __restrict__ query, const float* __restrict__ W,
    const float* __restrict__ b, float* __restrict__ qn) {
  const int row = blockIdx.x;     // query row
  const int j   = threadIdx.x;    // output feature
  __shared__ float4 qrow[64];
  __shared__ float red[256];
  if (j < 64) qrow[j] = ((const float4*)(query + (size_t)row * DIM))[j];
  __syncthreads();
  const float4* W4 = (const float4*)(W + (size_t)j * DIM);
  float acc = b[j];
  #pragma unroll 8
  for (int kk = 0; kk < 64; ++kk) {
    float4 w = W4[kk];
    float4 qv = qrow[kk];
    acc = fmaf(qv.x, w.x, acc);
    acc = fmaf(qv.y, w.y, acc);
    acc = fmaf(qv.z, w.z, acc);
    acc = fmaf(qv.w, w.w, acc);
  }
  red[j] = acc * acc;
  __syncthreads();
  #pragma unroll
  for (int s = 128; s > 0; s >>= 1) {
    if (j < s) red[j] += red[j + s];
    __syncthreads();
  }
  float norm = sqrtf(red[0]);
  qn[(size_t)row * DIM + j] = acc / fmaxf(norm, EPSN);   // coalesced
}

// ---------------- K2: per-key scale = 1/(max(||k||,eps)*temp), boost = 0.1*q --
__global__ __launch_bounds__(256) void knorm_kernel(
    const float* __restrict__ keys, const float* __restrict__ quality,
    const float* __restrict__ temperature,
    float* __restrict__ scale, float* __restrict__ boost) {
  const int tid = threadIdx.x;
  const int lane = tid & 63;
  const int row = blockIdx.x * 4 + (tid >> 6);   // one wave per key row
  float4 v = ((const float4*)(keys + (size_t)row * DIM))[lane];
  float ss = v.x * v.x + v.y * v.y + v.z * v.z + v.w * v.w;
  #pragma unroll
  for (int off = 32; off > 0; off >>= 1) ss += __shfl_xor(ss, off, 64);
  if (lane == 0) {
    float norm = sqrtf(ss);
    scale[row] = 1.0f / (fmaxf(norm, EPSN) * temperature[0]);
    boost[row] = 0.1f * quality[row];
  }
}

// ---------------- wave-cooperative exact top-32 extraction ------------------
// list: up to CAP float2 (val, idx-bits). Extracts TOPK largest by value.
// If gout != nullptr writes them there, else compacts into list[0..31].
// Returns the 32nd-largest value (new threshold); same in all lanes.
__device__ __attribute__((noinline)) float wave_extract(
    float2* list, int n, int lane, float2* gout) {
  float v0 = -INFINITY, v1 = -INFINITY, v2 = -INFINITY;
  float i0 = 0.f, i1 = 0.f, i2 = 0.f;
  if (lane < n)        { float2 e = list[lane];       v0 = e.x; i0 = e.y; }
  if (lane + 64 < n)   { float2 e = list[lane + 64];  v1 = e.x; i1 = e.y; }
  if (lane + 128 < n)  { float2 e = list[lane + 128]; v2 = e.x; i2 = e.y; }
  float m = -INFINITY;
  #pragma unroll 1
  for (int it = 0; it < TOPK; ++it) {
    float lm = fmaxf(v0, fmaxf(v1, v2));
    m = lm;
    #pragma unroll
    for (int off = 32; off > 0; off >>= 1) m = fmaxf(m, __shfl_xor(m, off, 64));
    u64 msk = __ballot(lm == m);
    int first = __ffsll((unsigned long long)msk) - 1;
    if (lane == first) {
      float2 e;
      if (v0 == lm)      { e = make_float2(v0, i0); v0 = -INFINITY; }
      else if (v1 == lm) { e = make_float2(v1, i1); v1 = -INFINITY; }
      else               { e = make_float2(v2, i2); v2 = -INFINITY; }
      if (gout) gout[it] = e; else list[it] = e;
    }
  }
  return m;
}

// ---------------- K3: fused sim-GEMM + streaming exact top-32 ---------------
__device__ __forceinline__ void gload_lds16(const float* __restrict__ g, void* l) {
  __builtin_amdgcn_global_load_lds(
      (const __attribute__((address_space(1))) void*)g,
      (__attribute__((address_space(3))) void*)l, 16, 0, 0);
}

// stage one 4-float d-chunk of a 1024-key tile (16 KB) into kb[0..1023]
__device__ __forceinline__ void stage_chunk(
    const float* __restrict__ keys, long nbase, int tile, int chunk,
    float4* kb, int tid) {
  const long nrow0 = nbase + (long)tile * NT + tid;
  const float* s0 = keys + (nrow0 << 8) + (chunk << 2);
  gload_lds16(s0, kb + tid);                 // lds dest contiguous by lane
  gload_lds16(s0 + (512L << 8), kb + tid + 512);
}

__global__ __launch_bounds__(512, 2) void sim_topk_kernel(
    const float* __restrict__ qn, const float* __restrict__ keys,
    const float* __restrict__ scale, const float* __restrict__ boost,
    float2* __restrict__ glists,    // [B_Q][NRANGES][CAP]
    float2* __restrict__ partials)  // [B_Q][NRANGES][TOPK]
{
  const int tid  = threadIdx.x;
  const int lane = tid & 63;
  const int wid  = __builtin_amdgcn_readfirstlane(tid >> 6);
  const int rg = blockIdx.x;      // key range
  const int qg = blockIdx.y;      // query group
  const int qbase = qg * QT + wid * WQ;             // scalar (SGPR)
  const long nbase = (long)rg * (N_K / NRANGES);

  __shared__ float4 kbuf[2][NT];     // 2 x 16 KB key double-buffer
  __shared__ float  qbuf[QT * DIM];  // 64 KB: this block's 64 normalized queries
  __shared__ int cnt[QT];

  if (tid < QT) cnt[tid] = 0;

  // stage all 64 query rows (contiguous 64 KB) + first key chunk; the first
  // c-loop barrier drains both (vmcnt 0) -- no extra sync needed.
  {
    const float* qsrc = qn + (size_t)(qg * QT) * DIM;
    #pragma unroll
    for (int it = 0; it < 8; ++it)
      gload_lds16(qsrc + (size_t)(it * 512 + tid) * 4, qbuf + (it * 512 + tid) * 4);
  }
  int buf = 0;
  stage_chunk(keys, nbase, 0, 0, &kbuf[0][0], tid);

  float tau_r[WQ];
  #pragma unroll
  for (int qi = 0; qi < WQ; ++qi) tau_r[qi] = -INFINITY;
  float2* const mybase = glists + ((size_t)qbase * NRANGES + rg) * CAP;

  #pragma unroll 1
  for (int t = 0; t < NTILES; ++t) {
    float acc[WQ][16];
    #pragma unroll
    for (int qi = 0; qi < WQ; ++qi)
      #pragma unroll
      for (int j = 0; j < 16; ++j) acc[qi][j] = 0.f;

    #pragma unroll 1
    for (int c = 0; c < 64; ++c) {          // d-chunks of 4
      __syncthreads();                       // drains previous stage (vmcnt 0)
      if (c < 63)                stage_chunk(keys, nbase, t,     c + 1, &kbuf[buf ^ 1][0], tid);
      else if (t < NTILES - 1)   stage_chunk(keys, nbase, t + 1, 0,     &kbuf[buf ^ 1][0], tid);
      // wave-uniform q fragments from LDS (broadcast ds_read_b128, no SMEM mixing)
      float4 qv[WQ];
      #pragma unroll
      for (int qi = 0; qi < WQ; ++qi)
        qv[qi] = *(const float4*)&qbuf[(wid * WQ + qi) * DIM + c * 4];
      #pragma unroll
      for (int j = 0; j < 16; ++j) {
        float4 kv = kbuf[buf][j * 64 + lane];
        #pragma unroll
        for (int qi = 0; qi < WQ; ++qi) {
          acc[qi][j] = fmaf(qv[qi].x, kv.x, acc[qi][j]);
          acc[qi][j] = fmaf(qv[qi].y, kv.y, acc[qi][j]);
          acc[qi][j] = fmaf(qv[qi].z, kv.z, acc[qi][j]);
          acc[qi][j] = fmaf(qv[qi].w, kv.w, acc[qi][j]);
        }
      }
      buf ^= 1;
    }

    // finalize sims, threshold-filter, append rare survivors
    const int ntile0 = t * NT;
    #pragma unroll 2
    for (int j = 0; j < 16; ++j) {
      const int nloc = ntile0 + j * 64 + lane;
      const long ng = nbase + nloc;
      const float sc = scale[ng];
      const float bo = boost[ng];
      bool any = false;
      #pragma unroll
      for (int qi = 0; qi < WQ; ++qi) {
        float v = fmaf(acc[qi][j], sc, bo);
        bool p = v > tau_r[qi];
        any |= p;
        if (p) {
          int pos = atomicAdd(&cnt[wid * WQ + qi], 1);
          mybase[(size_t)qi * NRANGES * CAP + pos] = make_float2(v, __int_as_float((int)ng));
        }
      }
      if (__any(any)) {
        #pragma unroll 1
        for (int qi = 0; qi < WQ; ++qi) {
          int cc = cnt[wid * WQ + qi];
          if (cc > FLUSH_AT) {
            tau_r[qi] = wave_extract(mybase + (size_t)qi * NRANGES * CAP, cc, lane, nullptr);
            if (lane == 0) cnt[wid * WQ + qi] = TOPK;
          }
        }
      }
    }
  }

  // final exact top-32 per (query, range)
  #pragma unroll 1
  for (int qi = 0; qi < WQ; ++qi) {
    float2* out = partials + ((size_t)(qbase + qi) * NRANGES + rg) * TOPK;
    wave_extract(mybase + (size_t)qi * NRANGES * CAP, cnt[wid * WQ + qi], lane, out);
  }
}

// ---------------- K4: merge partials, softmax, gather, weighted sums --------
__device__ __forceinline__ u32 f2ord(float f) {
  u32 u = __float_as_uint(f);
  return (u & 0x80000000u) ? ~u : (u | 0x80000000u);
}
__device__ __forceinline__ float ord2f(u32 o) {
  u32 u = (o & 0x80000000u) ? (o ^ 0x80000000u) : ~o;
  return __uint_as_float(u);
}

__global__ __launch_bounds__(256) void merge_kernel(
    const float2* __restrict__ partials, const float* __restrict__ keys,
    const float* __restrict__ values, float* __restrict__ out) {
  const int q = blockIdx.x;
  const int tid = threadIdx.x;
  __shared__ u64 skey[NRANGES * TOPK];           // 512
  for (int i = tid; i < 512; i += 256) {
    float2 e = partials[(size_t)q * 512 + i];
    int idx = __float_as_int(e.y);
    // key: orderable value in high 32, ~idx in low 32 => stable (low idx first)
    skey[i] = ((u64)f2ord(e.x) << 32) | (u32)(~(u32)idx);
  }
  __syncthreads();
  // bitonic sort, descending
  for (int k = 2; k <= 512; k <<= 1) {
    for (int jj = k >> 1; jj > 0; jj >>= 1) {
      for (int i = tid; i < 512; i += 256) {
        int ixj = i ^ jj;
        if (ixj > i) {
          u64 a = skey[i], bb = skey[ixj];
          bool up = ((i & k) == 0);
          if ((a < bb) == up) { skey[i] = bb; skey[ixj] = a; }
        }
      }
      __syncthreads();
    }
  }
  __shared__ float sval[TOPK];
  __shared__ int   sidx[TOPK];
  __shared__ float sscore[TOPK];
  if (tid < TOPK) {
    u64 kk = skey[tid];
    sval[tid] = ord2f((u32)(kk >> 32));
    sidx[tid] = (int)(~(u32)(kk & 0xffffffffu));
  }
  __syncthreads();
  if (tid < TOPK) {
    float m = sval[0];                     // sorted desc -> max
    float e = expf(sval[tid] - m);
    float s = e;
    #pragma unroll
    for (int off = 16; off > 0; off >>= 1) s += __shfl_xor(s, off, 64);
    sscore[tid] = e / s;
  }
  __syncthreads();
  if (tid < TOPK) out[(size_t)2 * B_Q * DIM + (size_t)q * TOPK + tid] = sscore[tid];
  float wk = 0.f, wv = 0.f;
  #pragma unroll 4
  for (int kk2 = 0; kk2 < TOPK; ++kk2) {
    float s = sscore[kk2];
    size_t idr = (size_t)sidx[kk2] * DIM + tid;
    wk = fmaf(s, keys[idr], wk);
    wv = fmaf(s, values[idr], wv);
  }
  out[(size_t)q * DIM + tid] = wk;
  out[(size_t)B_Q * DIM + (size_t)q * DIM + tid] = wv;
}

// ---------------- launch ----------------------------------------------------
extern "C" void kernel_launch(void* const* d_in, const int* in_sizes, int n_in,
                              void* d_out, int out_size, void* d_ws, size_t ws_size,
                              hipStream_t stream) {
  const float* query   = (const float*)d_in[0];
  const float* keys    = (const float*)d_in[1];
  const float* values  = (const float*)d_in[2];
  const float* quality = (const float*)d_in[3];
  const float* W       = (const float*)d_in[4];
  const float* b       = (const float*)d_in[5];
  const float* temp    = (const float*)d_in[6];
  float* out = (float*)d_out;
  float* ws = (float*)d_ws;

  float* qn    = ws;                                  // 262144 floats (1 MB)
  float* scale = ws + 262144;                         // 131072
  float* boost = ws + 393216;                         // 131072
  float2* partials = (float2*)(ws + 524288);          // 1024*16*32*2 floats (4 MB)
  float2* glists   = (float2*)(ws + 524288 + 1048576);// 1024*16*160*2 floats (21 MB)

  hipLaunchKernelGGL(qn_kernel, dim3(B_Q), dim3(256), 0, stream, query, W, b, qn);
  hipLaunchKernelGGL(knorm_kernel, dim3(N_K / 4), dim3(256), 0, stream,
                     keys, quality, temp, scale, boost);
  hipLaunchKernelGGL(sim_topk_kernel, dim3(NRANGES, QGROUPS), dim3(512), 0, stream,
                     qn, keys, scale, boost, glists, partials);
  hipLaunchKernelGGL(merge_kernel, dim3(B_Q), dim3(256), 0, stream,
                     partials, keys, values, out);
}

// Round 4
// 2060.008 us; speedup vs baseline: 2.9599x; 2.9599x over previous
//
#include <hip/hip_runtime.h>
#include <cstdint>
#include <cstddef>

#define B_Q   1024
#define N_K   131072
#define DIM   256
#define TOPK  32
#define EPSN  1e-12f

// main kernel config
#define NRANGES 16              // key ranges (blocks in x)
#define QGROUPS 16              // query groups (blocks in y)
#define QT      64              // queries per block
#define WQ      8               // queries per wave
#define NT      1024            // keys per tile
#define NTILES  8               // (N_K/NRANGES)/NT
#define CAP     160             // candidate list capacity per (q, range)
#define FLUSH_AT 96             // flush when cnt exceeds this
// bound proof: at each j-check cnt<=FLUSH_AT (else flushed to 32); one j adds
// <=64 appends per query => cnt <= 96+64 = 160 = CAP. never overflows.

typedef unsigned long long u64;
typedef unsigned int u32;

// ---------------- K1: qn = normalize(query @ W^T + b), row-major [B_Q][DIM] --
__global__ __launch_bounds__(256) void qn_kernel(
    const float* __restrict__ query, const float* __restrict__ W,
    const float* __restrict__ b, float* __restrict__ qn) {
  const int row = blockIdx.x;     // query row
  const int j   = threadIdx.x;    // output feature
  __shared__ float4 qrow[64];
  __shared__ float red[256];
  if (j < 64) qrow[j] = ((const float4*)(query + (size_t)row * DIM))[j];
  __syncthreads();
  const float4* W4 = (const float4*)(W + (size_t)j * DIM);
  float acc = b[j];
  #pragma unroll 8
  for (int kk = 0; kk < 64; ++kk) {
    float4 w = W4[kk];
    float4 qv = qrow[kk];
    acc = fmaf(qv.x, w.x, acc);
    acc = fmaf(qv.y, w.y, acc);
    acc = fmaf(qv.z, w.z, acc);
    acc = fmaf(qv.w, w.w, acc);
  }
  red[j] = acc * acc;
  __syncthreads();
  #pragma unroll
  for (int s = 128; s > 0; s >>= 1) {
    if (j < s) red[j] += red[j + s];
    __syncthreads();
  }
  float norm = sqrtf(red[0]);
  qn[(size_t)row * DIM + j] = acc / fmaxf(norm, EPSN);   // coalesced
}

// ---------------- K2: per-key scale = 1/(max(||k||,eps)*temp), boost = 0.1*q --
__global__ __launch_bounds__(256) void knorm_kernel(
    const float* __restrict__ keys, const float* __restrict__ quality,
    const float* __restrict__ temperature,
    float* __restrict__ scale, float* __restrict__ boost) {
  const int tid = threadIdx.x;
  const int lane = tid & 63;
  const int row = blockIdx.x * 4 + (tid >> 6);   // one wave per key row
  float4 v = ((const float4*)(keys + (size_t)row * DIM))[lane];
  float ss = v.x * v.x + v.y * v.y + v.z * v.z + v.w * v.w;
  #pragma unroll
  for (int off = 32; off > 0; off >>= 1) ss += __shfl_xor(ss, off, 64);
  if (lane == 0) {
    float norm = sqrtf(ss);
    scale[row] = 1.0f / (fmaxf(norm, EPSN) * temperature[0]);
    boost[row] = 0.1f * quality[row];
  }
}

// ---------------- wave-cooperative exact top-32 extraction ------------------
// list: up to CAP float2 (val, idx-bits). Extracts TOPK largest by value.
// If gout != nullptr writes them there, else compacts into list[0..31].
// Returns the 32nd-largest value (new threshold); same in all lanes.
__device__ __attribute__((noinline)) float wave_extract(
    float2* list, int n, int lane, float2* gout) {
  float v0 = -INFINITY, v1 = -INFINITY, v2 = -INFINITY;
  float i0 = 0.f, i1 = 0.f, i2 = 0.f;
  if (lane < n)        { float2 e = list[lane];       v0 = e.x; i0 = e.y; }
  if (lane + 64 < n)   { float2 e = list[lane + 64];  v1 = e.x; i1 = e.y; }
  if (lane + 128 < n)  { float2 e = list[lane + 128]; v2 = e.x; i2 = e.y; }
  float m = -INFINITY;
  #pragma unroll 1
  for (int it = 0; it < TOPK; ++it) {
    float lm = fmaxf(v0, fmaxf(v1, v2));
    m = lm;
    #pragma unroll
    for (int off = 32; off > 0; off >>= 1) m = fmaxf(m, __shfl_xor(m, off, 64));
    u64 msk = __ballot(lm == m);
    int first = __ffsll((unsigned long long)msk) - 1;
    if (lane == first) {
      float2 e;
      if (v0 == lm)      { e = make_float2(v0, i0); v0 = -INFINITY; }
      else if (v1 == lm) { e = make_float2(v1, i1); v1 = -INFINITY; }
      else               { e = make_float2(v2, i2); v2 = -INFINITY; }
      if (gout) gout[it] = e; else list[it] = e;
    }
  }
  return m;
}

// ---------------- K3: fused sim-GEMM + streaming exact top-32 ---------------
__device__ __forceinline__ void gload_lds16(const float* __restrict__ g, void* l) {
  __builtin_amdgcn_global_load_lds(
      (const __attribute__((address_space(1))) void*)g,
      (__attribute__((address_space(3))) void*)l, 16, 0, 0);
}

// stage one 4-float d-chunk of a 1024-key tile (16 KB) into kb[0..1023]
__device__ __forceinline__ void stage_chunk(
    const float* __restrict__ keys, long nbase, int tile, int chunk,
    float4* kb, int tid) {
  const long nrow0 = nbase + (long)tile * NT + tid;
  const float* s0 = keys + (nrow0 << 8) + (chunk << 2);
  gload_lds16(s0, kb + tid);                 // lds dest contiguous by lane
  gload_lds16(s0 + (512L << 8), kb + tid + 512);
}

__global__ __launch_bounds__(512, 2) void sim_topk_kernel(
    const float* __restrict__ qn, const float* __restrict__ keys,
    const float* __restrict__ scale, const float* __restrict__ boost,
    float2* __restrict__ glists,    // [B_Q][NRANGES][CAP]
    float2* __restrict__ partials)  // [B_Q][NRANGES][TOPK]
{
  const int tid  = threadIdx.x;
  const int lane = tid & 63;
  const int wid  = __builtin_amdgcn_readfirstlane(tid >> 6);
  const int rg = blockIdx.x;      // key range
  const int qg = blockIdx.y;      // query group
  const int qbase = qg * QT + wid * WQ;             // scalar (SGPR)
  const long nbase = (long)rg * (N_K / NRANGES);

  __shared__ float4 kbuf[2][NT];     // 2 x 16 KB key double-buffer
  __shared__ float  qbuf[QT * DIM];  // 64 KB: this block's 64 normalized queries
  __shared__ int cnt[QT];

  if (tid < QT) cnt[tid] = 0;

  // stage all 64 query rows (contiguous 64 KB) + first key chunk; the first
  // c-loop barrier drains both (vmcnt 0) -- no extra sync needed.
  {
    const float* qsrc = qn + (size_t)(qg * QT) * DIM;
    #pragma unroll
    for (int it = 0; it < 8; ++it)
      gload_lds16(qsrc + (size_t)(it * 512 + tid) * 4, qbuf + (it * 512 + tid) * 4);
  }
  int buf = 0;
  stage_chunk(keys, nbase, 0, 0, &kbuf[0][0], tid);

  // NOTE (rule #20): every access to acc[][] and tau_r[] below must be from a
  // FULLY-unrolled loop (compile-time indices) or the arrays demote to scratch.
  // Round-2 post-mortem: '#pragma unroll 2' on the epilogue caused exactly
  // that -- 34 GB of spill writes, VALUBusy 13%.
  float tau_r[WQ];
  #pragma unroll
  for (int qi = 0; qi < WQ; ++qi) tau_r[qi] = -INFINITY;
  float2* const mybase = glists + ((size_t)qbase * NRANGES + rg) * CAP;

  #pragma unroll 1
  for (int t = 0; t < NTILES; ++t) {
    float acc[WQ][16];
    #pragma unroll
    for (int qi = 0; qi < WQ; ++qi)
      #pragma unroll
      for (int j = 0; j < 16; ++j) acc[qi][j] = 0.f;

    #pragma unroll 1
    for (int c = 0; c < 64; ++c) {          // d-chunks of 4
      __syncthreads();                       // drains previous stage (vmcnt 0)
      if (c < 63)                stage_chunk(keys, nbase, t,     c + 1, &kbuf[buf ^ 1][0], tid);
      else if (t < NTILES - 1)   stage_chunk(keys, nbase, t + 1, 0,     &kbuf[buf ^ 1][0], tid);
      // wave-uniform q fragments from LDS (broadcast ds_read_b128)
      float4 qv[WQ];
      #pragma unroll
      for (int qi = 0; qi < WQ; ++qi)
        qv[qi] = *(const float4*)&qbuf[(wid * WQ + qi) * DIM + c * 4];
      #pragma unroll
      for (int j = 0; j < 16; ++j) {
        float4 kv = kbuf[buf][j * 64 + lane];
        #pragma unroll
        for (int qi = 0; qi < WQ; ++qi) {
          acc[qi][j] = fmaf(qv[qi].x, kv.x, acc[qi][j]);
          acc[qi][j] = fmaf(qv[qi].y, kv.y, acc[qi][j]);
          acc[qi][j] = fmaf(qv[qi].z, kv.z, acc[qi][j]);
          acc[qi][j] = fmaf(qv[qi].w, kv.w, acc[qi][j]);
        }
      }
      buf ^= 1;
    }

    // finalize sims, threshold-filter, append rare survivors
    const int ntile0 = t * NT;
    #pragma unroll                          // FULL unroll (16) -- keeps acc static
    for (int j = 0; j < 16; ++j) {
      const int nloc = ntile0 + j * 64 + lane;
      const long ng = nbase + nloc;
      const float sc = scale[ng];
      const float bo = boost[ng];
      bool any = false;
      #pragma unroll
      for (int qi = 0; qi < WQ; ++qi) {
        float v = fmaf(acc[qi][j], sc, bo);
        bool p = v > tau_r[qi];
        any |= p;
        if (p) {
          int pos = atomicAdd(&cnt[wid * WQ + qi], 1);
          mybase[(size_t)qi * NRANGES * CAP + pos] = make_float2(v, __int_as_float((int)ng));
        }
      }
      if (__any(any)) {
        #pragma unroll                      // FULL unroll (8) -- keeps tau_r static
        for (int qi = 0; qi < WQ; ++qi) {
          int cc = cnt[wid * WQ + qi];
          if (cc > FLUSH_AT) {
            tau_r[qi] = wave_extract(mybase + (size_t)qi * NRANGES * CAP, cc, lane, nullptr);
            if (lane == 0) cnt[wid * WQ + qi] = TOPK;
          }
        }
      }
    }
  }

  // final exact top-32 per (query, range) -- does not touch acc/tau_r
  #pragma unroll 1
  for (int qi = 0; qi < WQ; ++qi) {
    float2* out = partials + ((size_t)(qbase + qi) * NRANGES + rg) * TOPK;
    wave_extract(mybase + (size_t)qi * NRANGES * CAP, cnt[wid * WQ + qi], lane, out);
  }
}

// ---------------- K4: merge partials, softmax, gather, weighted sums --------
__device__ __forceinline__ u32 f2ord(float f) {
  u32 u = __float_as_uint(f);
  return (u & 0x80000000u) ? ~u : (u | 0x80000000u);
}
__device__ __forceinline__ float ord2f(u32 o) {
  u32 u = (o & 0x80000000u) ? (o ^ 0x80000000u) : ~o;
  return __uint_as_float(u);
}

__global__ __launch_bounds__(256) void merge_kernel(
    const float2* __restrict__ partials, const float* __restrict__ keys,
    const float* __restrict__ values, float* __restrict__ out) {
  const int q = blockIdx.x;
  const int tid = threadIdx.x;
  __shared__ u64 skey[NRANGES * TOPK];           // 512
  for (int i = tid; i < 512; i += 256) {
    float2 e = partials[(size_t)q * 512 + i];
    int idx = __float_as_int(e.y);
    // key: orderable value in high 32, ~idx in low 32 => stable (low idx first)
    skey[i] = ((u64)f2ord(e.x) << 32) | (u32)(~(u32)idx);
  }
  __syncthreads();
  // bitonic sort, descending
  for (int k = 2; k <= 512; k <<= 1) {
    for (int jj = k >> 1; jj > 0; jj >>= 1) {
      for (int i = tid; i < 512; i += 256) {
        int ixj = i ^ jj;
        if (ixj > i) {
          u64 a = skey[i], bb = skey[ixj];
          bool up = ((i & k) == 0);
          if ((a < bb) == up) { skey[i] = bb; skey[ixj] = a; }
        }
      }
      __syncthreads();
    }
  }
  __shared__ float sval[TOPK];
  __shared__ int   sidx[TOPK];
  __shared__ float sscore[TOPK];
  if (tid < TOPK) {
    u64 kk = skey[tid];
    sval[tid] = ord2f((u32)(kk >> 32));
    sidx[tid] = (int)(~(u32)(kk & 0xffffffffu));
  }
  __syncthreads();
  if (tid < TOPK) {
    float m = sval[0];                     // sorted desc -> max
    float e = expf(sval[tid] - m);
    float s = e;
    #pragma unroll
    for (int off = 16; off > 0; off >>= 1) s += __shfl_xor(s, off, 64);
    sscore[tid] = e / s;
  }
  __syncthreads();
  if (tid < TOPK) out[(size_t)2 * B_Q * DIM + (size_t)q * TOPK + tid] = sscore[tid];
  float wk = 0.f, wv = 0.f;
  #pragma unroll 4
  for (int kk2 = 0; kk2 < TOPK; ++kk2) {
    float s = sscore[kk2];
    size_t idr = (size_t)sidx[kk2] * DIM + tid;
    wk = fmaf(s, keys[idr], wk);
    wv = fmaf(s, values[idr], wv);
  }
  out[(size_t)q * DIM + tid] = wk;
  out[(size_t)B_Q * DIM + (size_t)q * DIM + tid] = wv;
}

// ---------------- launch ----------------------------------------------------
extern "C" void kernel_launch(void* const* d_in, const int* in_sizes, int n_in,
                              void* d_out, int out_size, void* d_ws, size_t ws_size,
                              hipStream_t stream) {
  const float* query   = (const float*)d_in[0];
  const float* keys    = (const float*)d_in[1];
  const float* values  = (const float*)d_in[2];
  const float* quality = (const float*)d_in[3];
  const float* W       = (const float*)d_in[4];
  const float* b       = (const float*)d_in[5];
  const float* temp    = (const float*)d_in[6];
  float* out = (float*)d_out;
  float* ws = (float*)d_ws;

  float* qn    = ws;                                  // 262144 floats (1 MB)
  float* scale = ws + 262144;                         // 131072
  float* boost = ws + 393216;                         // 131072
  float2* partials = (float2*)(ws + 524288);          // 1024*16*32*2 floats (4 MB)
  float2* glists   = (float2*)(ws + 524288 + 1048576);// 1024*16*160*2 floats (21 MB)

  hipLaunchKernelGGL(qn_kernel, dim3(B_Q), dim3(256), 0, stream, query, W, b, qn);
  hipLaunchKernelGGL(knorm_kernel, dim3(N_K / 4), dim3(256), 0, stream,
                     keys, quality, temp, scale, boost);
  hipLaunchKernelGGL(sim_topk_kernel, dim3(NRANGES, QGROUPS), dim3(512), 0, stream,
                     qn, keys, scale, boost, glists, partials);
  hipLaunchKernelGGL(merge_kernel, dim3(B_Q), dim3(256), 0, stream,
                     partials, keys, values, out);
}

// Round 5
// 1993.517 us; speedup vs baseline: 3.0586x; 1.0334x over previous
//
#include <hip/hip_runtime.h>
#include <cstdint>
#include <cstddef>

#define B_Q   1024
#define N_K   131072
#define DIM   256
#define TOPK  32
#define EPSN  1e-12f

// main kernel config
#define NRANGES 16              // key ranges (blocks in x)
#define QGROUPS 32              // query groups (blocks in y)
#define QT      32              // queries per block (4 waves x 8)
#define WQ      8               // queries per wave
#define NT      512             // keys per tile (8 rows of 64 lanes)
#define NTILES  16              // (N_K/NRANGES)/NT
#define CAP     160             // candidate list capacity per (q, range)
#define FLUSH_AT 96             // flush when cnt exceeds this
// bound proof: at each j-check cnt<=FLUSH_AT (else flushed to 32); one j adds
// <=64 appends per query => cnt <= 96+64 = 160 = CAP. never overflows.

typedef unsigned long long u64;
typedef unsigned int u32;

// ---------------- K1: qn = normalize(query @ W^T + b), row-major [B_Q][DIM] --
__global__ __launch_bounds__(256) void qn_kernel(
    const float* __restrict__ query, const float* __restrict__ W,
    const float* __restrict__ b, float* __restrict__ qn) {
  const int row = blockIdx.x;     // query row
  const int j   = threadIdx.x;    // output feature
  __shared__ float4 qrow[64];
  __shared__ float red[256];
  if (j < 64) qrow[j] = ((const float4*)(query + (size_t)row * DIM))[j];
  __syncthreads();
  const float4* W4 = (const float4*)(W + (size_t)j * DIM);
  float acc = b[j];
  #pragma unroll 8
  for (int kk = 0; kk < 64; ++kk) {
    float4 w = W4[kk];
    float4 qv = qrow[kk];
    acc = fmaf(qv.x, w.x, acc);
    acc = fmaf(qv.y, w.y, acc);
    acc = fmaf(qv.z, w.z, acc);
    acc = fmaf(qv.w, w.w, acc);
  }
  red[j] = acc * acc;
  __syncthreads();
  #pragma unroll
  for (int s = 128; s > 0; s >>= 1) {
    if (j < s) red[j] += red[j + s];
    __syncthreads();
  }
  float norm = sqrtf(red[0]);
  qn[(size_t)row * DIM + j] = acc / fmaxf(norm, EPSN);   // coalesced
}

// ---------------- K2: per-key scale = 1/(max(||k||,eps)*temp), boost = 0.1*q --
__global__ __launch_bounds__(256) void knorm_kernel(
    const float* __restrict__ keys, const float* __restrict__ quality,
    const float* __restrict__ temperature,
    float* __restrict__ scale, float* __restrict__ boost) {
  const int tid = threadIdx.x;
  const int lane = tid & 63;
  const int row = blockIdx.x * 4 + (tid >> 6);   // one wave per key row
  float4 v = ((const float4*)(keys + (size_t)row * DIM))[lane];
  float ss = v.x * v.x + v.y * v.y + v.z * v.z + v.w * v.w;
  #pragma unroll
  for (int off = 32; off > 0; off >>= 1) ss += __shfl_xor(ss, off, 64);
  if (lane == 0) {
    float norm = sqrtf(ss);
    scale[row] = 1.0f / (fmaxf(norm, EPSN) * temperature[0]);
    boost[row] = 0.1f * quality[row];
  }
}

// ---------------- wave-cooperative exact top-32 extraction ------------------
// list: up to CAP float2 (val, idx-bits). Extracts TOPK largest by value.
// If gout != nullptr writes them there, else compacts into list[0..31].
// Returns the 32nd-largest value (new threshold); same in all lanes.
__device__ __attribute__((noinline)) float wave_extract(
    float2* list, int n, int lane, float2* gout) {
  float v0 = -INFINITY, v1 = -INFINITY, v2 = -INFINITY;
  float i0 = 0.f, i1 = 0.f, i2 = 0.f;
  if (lane < n)        { float2 e = list[lane];       v0 = e.x; i0 = e.y; }
  if (lane + 64 < n)   { float2 e = list[lane + 64];  v1 = e.x; i1 = e.y; }
  if (lane + 128 < n)  { float2 e = list[lane + 128]; v2 = e.x; i2 = e.y; }
  float m = -INFINITY;
  #pragma unroll 1
  for (int it = 0; it < TOPK; ++it) {
    float lm = fmaxf(v0, fmaxf(v1, v2));
    m = lm;
    #pragma unroll
    for (int off = 32; off > 0; off >>= 1) m = fmaxf(m, __shfl_xor(m, off, 64));
    u64 msk = __ballot(lm == m);
    int first = __ffsll((unsigned long long)msk) - 1;
    if (lane == first) {
      float2 e;
      if (v0 == lm)      { e = make_float2(v0, i0); v0 = -INFINITY; }
      else if (v1 == lm) { e = make_float2(v1, i1); v1 = -INFINITY; }
      else               { e = make_float2(v2, i2); v2 = -INFINITY; }
      if (gout) gout[it] = e; else list[it] = e;
    }
  }
  return m;
}

// ---------------- K3: fused sim-GEMM + streaming exact top-32 ---------------
__device__ __forceinline__ void gload_lds16(const float* __restrict__ g, void* l) {
  __builtin_amdgcn_global_load_lds(
      (const __attribute__((address_space(1))) void*)g,
      (__attribute__((address_space(3))) void*)l, 16, 0, 0);
}

// stage one phase = two 4-float d-chunks (c2=0,1) of a 512-key tile (16 KB)
// layout: kb[c2*512 + key_local] (chunk-major keeps ds_read_b128 conflict-free)
__device__ __forceinline__ void stage_phase(
    const float* __restrict__ keys, long nbase, int t, int c,
    float4* kb, int tid) {
  #pragma unroll
  for (int i = 0; i < 4; ++i) {
    const int c2   = i >> 1;
    const int keyl = (i & 1) * 256 + tid;
    const float* src = keys + ((size_t)(nbase + t * NT + keyl) << 8) + c * 8 + c2 * 4;
    gload_lds16(src, kb + c2 * 512 + keyl);   // dest = uniform + tid*16B per wave
  }
}

// block = 256 threads (4 waves), 2 blocks/CU (LDS 64.1 KB) so one block's
// barrier drain overlaps the other block's FMA stream (m114 mechanism).
__global__ __launch_bounds__(256, 2) void sim_topk_kernel(
    const float* __restrict__ qn, const float* __restrict__ keys,
    const float* __restrict__ scale, const float* __restrict__ boost,
    float2* __restrict__ glists,    // [B_Q][NRANGES][CAP]
    float2* __restrict__ partials)  // [B_Q][NRANGES][TOPK]
{
  const int tid  = threadIdx.x;
  const int lane = tid & 63;
  const int wid  = __builtin_amdgcn_readfirstlane(tid >> 6);   // 0..3
  const int rg = blockIdx.x;      // key range
  const int qg = blockIdx.y;      // query group
  const int qbase = qg * QT + wid * WQ;             // scalar (SGPR)
  const int qloc0 = wid * WQ;                       // local query of this wave
  const long nbase = (long)rg * (N_K / NRANGES);

  __shared__ float4 kbuf4[2][2 * NT];  // [buf][c2*512+key]: 32 KB
  __shared__ float  qbuf[QT * DIM];    // 32 KB: this block's 32 normalized queries
  __shared__ int cnt[QT];

  if (tid < QT) cnt[tid] = 0;

  // stage all 32 query rows (32 KB) + first key phase; the first c-loop
  // barrier drains both (vmcnt 0) -- no extra sync needed.
  {
    const float* qsrc = qn + (size_t)(qg * QT) * DIM;
    #pragma unroll
    for (int it = 0; it < 8; ++it)
      gload_lds16(qsrc + (size_t)(it * 256 + tid) * 4, qbuf + (it * 256 + tid) * 4);
  }
  int buf = 0;
  stage_phase(keys, nbase, 0, 0, &kbuf4[0][0], tid);

  // NOTE (rule #20): every access to acc[][] and tau_r[] below must be from a
  // FULLY-unrolled loop (compile-time indices) or the arrays demote to scratch
  // (round-2: 34 GB spill). acc is 8x8=64 regs -- sized to stay in arch VGPRs
  // (round-4: 8x16=128 acc got banked to AGPRs at VGPR_Count=108 -> accvgpr
  // shuttling inflated VALU ~1.5x).
  float tau_r[WQ];
  #pragma unroll
  for (int qi = 0; qi < WQ; ++qi) tau_r[qi] = -INFINITY;
  float2* const mybase = glists + ((size_t)qbase * NRANGES + rg) * CAP;

  #pragma unroll 1
  for (int t = 0; t < NTILES; ++t) {
    float acc[WQ][8];
    #pragma unroll
    for (int qi = 0; qi < WQ; ++qi)
      #pragma unroll
      for (int j = 0; j < 8; ++j) acc[qi][j] = 0.f;

    #pragma unroll 1
    for (int c = 0; c < 32; ++c) {          // d-chunks of 8 floats
      __syncthreads();                       // drains previous stage (vmcnt 0)
      if (c < 31)                stage_phase(keys, nbase, t,     c + 1, &kbuf4[buf ^ 1][0], tid);
      else if (t < NTILES - 1)   stage_phase(keys, nbase, t + 1, 0,     &kbuf4[buf ^ 1][0], tid);
      #pragma unroll
      for (int c2 = 0; c2 < 2; ++c2) {
        // wave-uniform q fragments from LDS (broadcast ds_read_b128)
        float4 qv[WQ];
        #pragma unroll
        for (int qi = 0; qi < WQ; ++qi)
          qv[qi] = *(const float4*)&qbuf[(qloc0 + qi) * DIM + c * 8 + c2 * 4];
        #pragma unroll
        for (int j = 0; j < 8; ++j) {
          float4 kv = kbuf4[buf][c2 * 512 + j * 64 + lane];
          #pragma unroll
          for (int qi = 0; qi < WQ; ++qi) {
            acc[qi][j] = fmaf(qv[qi].x, kv.x, acc[qi][j]);
            acc[qi][j] = fmaf(qv[qi].y, kv.y, acc[qi][j]);
            acc[qi][j] = fmaf(qv[qi].z, kv.z, acc[qi][j]);
            acc[qi][j] = fmaf(qv[qi].w, kv.w, acc[qi][j]);
          }
        }
      }
      buf ^= 1;
    }

    // finalize sims, threshold-filter, append rare survivors
    const int ntile0 = t * NT;
    #pragma unroll                          // FULL unroll (8) -- keeps acc static
    for (int j = 0; j < 8; ++j) {
      const int nloc = ntile0 + j * 64 + lane;
      const long ng = nbase + nloc;
      const float sc = scale[ng];
      const float bo = boost[ng];
      bool any = false;
      #pragma unroll
      for (int qi = 0; qi < WQ; ++qi) {
        float v = fmaf(acc[qi][j], sc, bo);
        bool p = v > tau_r[qi];
        any |= p;
        if (p) {
          int pos = atomicAdd(&cnt[wid * WQ + qi], 1);
          mybase[(size_t)qi * NRANGES * CAP + pos] = make_float2(v, __int_as_float((int)ng));
        }
      }
      if (__any(any)) {
        #pragma unroll                      // FULL unroll (8) -- keeps tau_r static
        for (int qi = 0; qi < WQ; ++qi) {
          int cc = cnt[wid * WQ + qi];
          if (cc > FLUSH_AT) {
            tau_r[qi] = wave_extract(mybase + (size_t)qi * NRANGES * CAP, cc, lane, nullptr);
            if (lane == 0) cnt[wid * WQ + qi] = TOPK;
          }
        }
      }
    }
  }

  // final exact top-32 per (query, range) -- does not touch acc/tau_r
  #pragma unroll 1
  for (int qi = 0; qi < WQ; ++qi) {
    float2* out = partials + ((size_t)(qbase + qi) * NRANGES + rg) * TOPK;
    wave_extract(mybase + (size_t)qi * NRANGES * CAP, cnt[wid * WQ + qi], lane, out);
  }
}

// ---------------- K4: merge partials, softmax, gather, weighted sums --------
__device__ __forceinline__ u32 f2ord(float f) {
  u32 u = __float_as_uint(f);
  return (u & 0x80000000u) ? ~u : (u | 0x80000000u);
}
__device__ __forceinline__ float ord2f(u32 o) {
  u32 u = (o & 0x80000000u) ? (o ^ 0x80000000u) : ~o;
  return __uint_as_float(u);
}

__global__ __launch_bounds__(256) void merge_kernel(
    const float2* __restrict__ partials, const float* __restrict__ keys,
    const float* __restrict__ values, float* __restrict__ out) {
  const int q = blockIdx.x;
  const int tid = threadIdx.x;
  __shared__ u64 skey[NRANGES * TOPK];           // 512
  for (int i = tid; i < 512; i += 256) {
    float2 e = partials[(size_t)q * 512 + i];
    int idx = __float_as_int(e.y);
    // key: orderable value in high 32, ~idx in low 32 => stable (low idx first)
    skey[i] = ((u64)f2ord(e.x) << 32) | (u32)(~(u32)idx);
  }
  __syncthreads();
  // bitonic sort, descending
  for (int k = 2; k <= 512; k <<= 1) {
    for (int jj = k >> 1; jj > 0; jj >>= 1) {
      for (int i = tid; i < 512; i += 256) {
        int ixj = i ^ jj;
        if (ixj > i) {
          u64 a = skey[i], bb = skey[ixj];
          bool up = ((i & k) == 0);
          if ((a < bb) == up) { skey[i] = bb; skey[ixj] = a; }
        }
      }
      __syncthreads();
    }
  }
  __shared__ float sval[TOPK];
  __shared__ int   sidx[TOPK];
  __shared__ float sscore[TOPK];
  if (tid < TOPK) {
    u64 kk = skey[tid];
    sval[tid] = ord2f((u32)(kk >> 32));
    sidx[tid] = (int)(~(u32)(kk & 0xffffffffu));
  }
  __syncthreads();
  if (tid < TOPK) {
    float m = sval[0];                     // sorted desc -> max
    float e = expf(sval[tid] - m);
    float s = e;
    #pragma unroll
    for (int off = 16; off > 0; off >>= 1) s += __shfl_xor(s, off, 64);
    sscore[tid] = e / s;
  }
  __syncthreads();
  if (tid < TOPK) out[(size_t)2 * B_Q * DIM + (size_t)q * TOPK + tid] = sscore[tid];
  float wk = 0.f, wv = 0.f;
  #pragma unroll 4
  for (int kk2 = 0; kk2 < TOPK; ++kk2) {
    float s = sscore[kk2];
    size_t idr = (size_t)sidx[kk2] * DIM + tid;
    wk = fmaf(s, keys[idr], wk);
    wv = fmaf(s, values[idr], wv);
  }
  out[(size_t)q * DIM + tid] = wk;
  out[(size_t)B_Q * DIM + (size_t)q * DIM + tid] = wv;
}

// ---------------- launch ----------------------------------------------------
extern "C" void kernel_launch(void* const* d_in, const int* in_sizes, int n_in,
                              void* d_out, int out_size, void* d_ws, size_t ws_size,
                              hipStream_t stream) {
  const float* query   = (const float*)d_in[0];
  const float* keys    = (const float*)d_in[1];
  const float* values  = (const float*)d_in[2];
  const float* quality = (const float*)d_in[3];
  const float* W       = (const float*)d_in[4];
  const float* b       = (const float*)d_in[5];
  const float* temp    = (const float*)d_in[6];
  float* out = (float*)d_out;
  float* ws = (float*)d_ws;

  float* qn    = ws;                                  // 262144 floats (1 MB)
  float* scale = ws + 262144;                         // 131072
  float* boost = ws + 393216;                         // 131072
  float2* partials = (float2*)(ws + 524288);          // 1024*16*32*2 floats (4 MB)
  float2* glists   = (float2*)(ws + 524288 + 1048576);// 1024*16*160*2 floats (21 MB)

  hipLaunchKernelGGL(qn_kernel, dim3(B_Q), dim3(256), 0, stream, query, W, b, qn);
  hipLaunchKernelGGL(knorm_kernel, dim3(N_K / 4), dim3(256), 0, stream,
                     keys, quality, temp, scale, boost);
  hipLaunchKernelGGL(sim_topk_kernel, dim3(NRANGES, QGROUPS), dim3(256), 0, stream,
                     qn, keys, scale, boost, glists, partials);
  hipLaunchKernelGGL(merge_kernel, dim3(B_Q), dim3(256), 0, stream,
                     partials, keys, values, out);
}